// Round 17
// baseline (226.333 us; speedup 1.0000x reference)
//
#include <hip/hip_runtime.h>
#include <math.h>

#define Kk 8
#define Bb 32
#define Cc 3
#define HW 36864          // 192*192
#define HW4 9216          // float4s per plane
#define CHW 110592        // 3*HW
#define CHW4 27648        // float4s per (k,b) image
#define BCHW 3538944      // B*C*HW
#define OUTMAIN 31850496  // 9*BCHW : index tail start in d_out (elements)
#define NCH 36            // chunks per batch (1024 px each)
#define QK 27             // per-k partial slots: spec[c][3] (24) + plain[3]
#define PARTN 7776        // 8*QK*NCH per batch
#define INVVAR 11.11111111111111f
#define EPSf 1e-5f

__device__ __forceinline__ int clampK(int v) { return v < 0 ? 0 : (v > Kk - 1 ? Kk - 1 : v); }
__device__ __forceinline__ float4 ld4(const float* p) { return *reinterpret_cast<const float4*>(p); }
__device__ __forceinline__ void st4(float* p, float4 v) { *reinterpret_cast<float4*>(p) = v; }

// ---------------------------------------------------------------------------
// Kernel 1: PHASE A: recon -> out[0], sd = shp*sum_c(apc-img)^2 (r7 body).
// PHASE B (after barrier): spec0 accumulate (t=0: P=1, mask=0xFF) reading
// shp/sd from cache (sd just written by this block, L1-hot) -> partials0.
// Replaces the standalone spec0 kernel. grid: 1152 x 256.
// ---------------------------------------------------------------------------
__global__ __launch_bounds__(256, 3) void k_pre_spec0(
    const float* __restrict__ images, const float* __restrict__ apc,
    const float* __restrict__ shp, const float* __restrict__ zeta,
    const float* __restrict__ back, float* __restrict__ out,
    float* __restrict__ sd, float* __restrict__ pcur)
{
    int b = blockIdx.x / NCH, ch = blockIdx.x % NCH;
    int tid = threadIdx.x;
    int pix = ch * 1024 + tid * 4;

    // ---------------- PHASE A (identical math to r7/r16 pre) ----------------
    {
        float4 img[Cc], bk[Cc], rec[Cc];
#pragma unroll
        for (int c = 0; c < Cc; ++c) {
            img[c] = ld4(images + (size_t)(b * Cc + c) * HW + pix);
            bk[c]  = ld4(back   + (size_t)(b * Cc + c) * HW + pix);
            rec[c] = make_float4(0.f, 0.f, 0.f, 0.f);
        }
        float cum0 = 1.f, cum1 = 1.f, cum2 = 1.f, cum3 = 1.f;
#pragma unroll
        for (int k = 0; k < Kk; ++k) {
            float4 s = ld4(shp + (size_t)(k * Bb + b) * HW + pix);
            float z = zeta[k * Bb + b];
            float x0 = s.x * z, x1 = s.y * z, x2 = s.z * z, x3 = s.w * z;
            float g0 = x0 * cum0, g1 = x1 * cum1, g2 = x2 * cum2, g3 = x3 * cum3;
            float df0 = 0.f, df1 = 0.f, df2 = 0.f, df3 = 0.f;
#pragma unroll
            for (int c = 0; c < Cc; ++c) {
                float4 av = ld4(apc + ((size_t)(k * Bb + b) * Cc + c) * HW + pix);
                float d0 = av.x - img[c].x, d1 = av.y - img[c].y;
                float d2 = av.z - img[c].z, d3 = av.w - img[c].w;
                df0 += d0 * d0; df1 += d1 * d1; df2 += d2 * d2; df3 += d3 * d3;
                rec[c].x += g0 * av.x; rec[c].y += g1 * av.y;
                rec[c].z += g2 * av.z; rec[c].w += g3 * av.w;
            }
            st4(sd + (size_t)(k * Bb + b) * HW + pix,
                make_float4(s.x * df0, s.y * df1, s.z * df2, s.w * df3));
            cum0 *= (1.f - x0); cum1 *= (1.f - x1); cum2 *= (1.f - x2); cum3 *= (1.f - x3);
        }
#pragma unroll
        for (int c = 0; c < Cc; ++c) {
            st4(out + (size_t)(b * Cc + c) * HW + pix,
                make_float4(rec[c].x + cum0 * bk[c].x, rec[c].y + cum1 * bk[c].y,
                            rec[c].z + cum2 * bk[c].z, rec[c].w + cum3 * bk[c].w));
        }
    }
    __syncthreads();   // sd for this chunk complete & visible block-wide

    // ---------------- PHASE B: spec0 (P==1, all candidates) ----------------
    int g = tid >> 5, l = tid & 31;
    float pd = 0.f, pa = 0.f, pm = -1e30f;
    float accd[Kk], acca[Kk], accm[Kk];
#pragma unroll
    for (int j = 0; j < Kk; ++j) { accd[j] = 0.f; acca[j] = 0.f; accm[j] = -1e30f; }

    for (int i = 0; i < 8; ++i) {
        int px = ch * 1024 + (i * 32 + l) * 4;
        float4 sc[Kk];
#pragma unroll
        for (int j = 0; j < Kk; ++j) {
            int plane = (g + j) & 7;
            sc[j] = ld4(shp + (size_t)(plane * Bb + b) * HW + px);
        }
        float4 sdg = ld4(sd + (size_t)(g * Bb + b) * HW + px);
        float4 sg = sc[0];                         // target plane == slot 0

#define SPEC_J(j) { float u = 1.f - SCV; float tt = m_ * u; \
        acca[j] += tt; accm[j] = fmaxf(accm[j], tt); accd[j] = fmaf(v_, u, accd[j]); }
#define DO_ELEM(e) { float m_ = sg.e; float v_ = sdg.e; \
        pd += v_; pa += m_; pm = fmaxf(pm, m_); \
        { const int j=0; float SCV=sc[0].e; SPEC_J(0) } { const int j=1; float SCV=sc[1].e; SPEC_J(1) } \
        { const int j=2; float SCV=sc[2].e; SPEC_J(2) } { const int j=3; float SCV=sc[3].e; SPEC_J(3) } \
        { const int j=4; float SCV=sc[4].e; SPEC_J(4) } { const int j=5; float SCV=sc[5].e; SPEC_J(5) } \
        { const int j=6; float SCV=sc[6].e; SPEC_J(6) } { const int j=7; float SCV=sc[7].e; SPEC_J(7) } }
        DO_ELEM(x) DO_ELEM(y) DO_ELEM(z) DO_ELEM(w)
#undef DO_ELEM
#undef SPEC_J
    }

    __shared__ float ls[Kk][32][29];
    float* mine = ls[g][l];
#pragma unroll
    for (int j = 0; j < Kk; ++j) {
        mine[j * 3 + 0] = accd[j]; mine[j * 3 + 1] = acca[j]; mine[j * 3 + 2] = accm[j];
    }
    mine[24] = pd; mine[25] = pa; mine[26] = pm;
    __syncthreads();
    for (int st = 16; st > 0; st >>= 1) {
        if (l < st) {
            float* other = ls[g][l + st];
#pragma unroll
            for (int q = 0; q < QK; ++q)
                mine[q] = (q % 3 == 2) ? fmaxf(mine[q], other[q]) : (mine[q] + other[q]);
        }
        __syncthreads();
    }
    if (l == 0) {
#pragma unroll
        for (int j = 0; j < Kk; ++j) {
            int c = (g + j) & 7;                   // slot j holds candidate plane c
#pragma unroll
            for (int comp = 0; comp < 3; ++comp)
                pcur[(size_t)b * PARTN + (size_t)(g * QK + c * 3 + comp) * NCH + ch] = mine[j * 3 + comp];
        }
#pragma unroll
        for (int q = 24; q < QK; ++q)
            pcur[(size_t)b * PARTN + (size_t)(g * QK + q) * NCH + ch] = mine[q];
    }
}

// ---------------------------------------------------------------------------
// Head: resolve idx_{t-2} (plain) then idx_{t-1} (spec slice). Unchanged r12.
// ---------------------------------------------------------------------------
__device__ __forceinline__ void run_head(
    const float* __restrict__ pprev, const float* __restrict__ zeta,
    float* idxf, int b, int t, int write_idx, int tid,
    float* sv, int* s_ia, int* s_ib, int* s_mask)
{
    if (tid < 24) {
        int k = tid / 3, comp = tid - k * 3;
        float v = (comp == 2) ? -1e30f : 0.f;
        const float* src = pprev + (size_t)b * PARTN + (size_t)(k * QK + 24 + comp) * NCH;
        for (int j = 0; j < NCH; ++j) {
            float x = src[j];
            v = (comp == 2) ? fmaxf(v, x) : (v + x);
        }
        sv[tid] = v;
    }
    __syncthreads();
    if (tid == 0) {
        float best = -1e30f; int bi = 0;
        for (int k = 0; k < Kk; ++k) {
            float coef = 1.f;
            for (int j = 0; j < t - 2; ++j)
                if (clampK((int)idxf[j * Bb + b]) == k) coef = -1.f;
            float sc = coef * sv[3 * k + 2] * zeta[k * Bb + b] *
                       expf(-0.5f * INVVAR * sv[3 * k + 0] / (sv[3 * k + 1] + EPSf));
            if (sc > best) { best = sc; bi = k; }
        }
        *s_ia = bi;
    }
    __syncthreads();
    int ia = *s_ia;
    if (tid < 24) {
        int k = tid / 3, comp = tid - k * 3;
        float v = (comp == 2) ? -1e30f : 0.f;
        const float* src = pprev + (size_t)b * PARTN + (size_t)(k * QK + ia * 3 + comp) * NCH;
        for (int j = 0; j < NCH; ++j) {
            float x = src[j];
            v = (comp == 2) ? fmaxf(v, x) : (v + x);
        }
        sv[tid] = v;
    }
    __syncthreads();
    if (tid == 0) {
        float best = -1e30f; int bi = 0;
        for (int k = 0; k < Kk; ++k) {
            float coef = 1.f;
            for (int j = 0; j < t - 2; ++j)
                if (clampK((int)idxf[j * Bb + b]) == k) coef = -1.f;
            if (ia == k) coef = -1.f;
            float sc = coef * sv[3 * k + 2] * zeta[k * Bb + b] *
                       expf(-0.5f * INVVAR * sv[3 * k + 0] / (sv[3 * k + 1] + EPSf));
            if (sc > best) { best = sc; bi = k; }
        }
        *s_ib = bi;
        int mask = 0xFF;
        for (int j = 0; j < t - 2; ++j) mask &= ~(1 << clampK((int)idxf[j * Bb + b]));
        mask &= ~(1 << ia); mask &= ~(1 << bi);
        *s_mask = mask;
        if (write_idx) {
            idxf[(t - 2) * Bb + b] = (float)ia;
            idxf[(t - 1) * Bb + b] = (float)bi;
        }
    }
    __syncthreads();
}

// ---------------------------------------------------------------------------
// Kernel 2 (t=2,4,6): head -> copies -> race-free P phase -> accumulate with
// PLANE-SLOT ROTATION (group g loads plane (g+j)&7 into slot j; target =
// slot 0, duplicate sg load eliminated; windows in order => per-candidate
// summation order identical to r12/r14). grid: 1152 x 256.
// ---------------------------------------------------------------------------
__global__ __launch_bounds__(256, 4) void k_spec(
    const float* __restrict__ shp, const float* __restrict__ sd,
    float* __restrict__ Pbuf, float* idxf, const float* __restrict__ zeta,
    const float* __restrict__ pprev, float* __restrict__ pcur,
    const float* __restrict__ apc, float* __restrict__ gout,
    int t, int do_copy)
{
    int b = blockIdx.x / NCH, ch = blockIdx.x % NCH;
    int tid = threadIdx.x;
    int g = tid >> 5, l = tid & 31;

    __shared__ float sv[24];
    __shared__ int s_ia, s_ib, s_mask;
    run_head(pprev, zeta, idxf, b, t, (ch == 0), tid, sv, &s_ia, &s_ib, &s_mask);
    int ia = s_ia, ib = s_ib, mask = s_mask;

    // ---- fused gather copy for steps t-2, t-1 (ws path only) ----
    if (do_copy) {
        const float4* apc4 = reinterpret_cast<const float4*>(apc);
        float4* out4 = reinterpret_cast<float4*>(gout);
        const float4* src0 = apc4 + (size_t)(ia * Bb + b) * CHW4;
        const float4* src1 = apc4 + (size_t)(ib * Bb + b) * CHW4;
        float4* dst0 = out4 + (size_t)((t - 1) * Bb + b) * CHW4;   // out[1+(t-2)]
        float4* dst1 = out4 + (size_t)(t * Bb + b) * CHW4;         // out[1+(t-1)]
        int cb = ch * 768 + tid;
#pragma unroll
        for (int i = 0; i < 3; ++i) {
            dst0[cb + i * 256] = src0[cb + i * 256];
            dst1[cb + i * 256] = src1[cb + i * 256];
        }
    }

    const size_t bHW = (size_t)b * HW;

    // ---- P PHASE (race-free, r16): compute+store before loop, barrier ----
    {
        int px = ch * 1024 + tid * 4;
        float4 p0 = make_float4(1.f, 1.f, 1.f, 1.f);
        if (t > 2) p0 = ld4(Pbuf + bHW + px);
        float4 sa = ld4(shp + (size_t)(ia * Bb + b) * HW + px);
        float4 sb = ld4(shp + (size_t)(ib * Bb + b) * HW + px);
        float4 p1, P;
        p1.x = p0.x * (1.f - sa.x * p0.x); p1.y = p0.y * (1.f - sa.y * p0.y);
        p1.z = p0.z * (1.f - sa.z * p0.z); p1.w = p0.w * (1.f - sa.w * p0.w);
        P.x = p1.x * (1.f - sb.x * p1.x); P.y = p1.y * (1.f - sb.y * p1.y);
        P.z = p1.z * (1.f - sb.z * p1.z); P.w = p1.w * (1.f - sb.w * p1.w);
        st4(Pbuf + bHW + px, P);
        __syncthreads();
    }

    int um[Kk];
#pragma unroll
    for (int j = 0; j < Kk; ++j) um[j] = (mask >> ((g + j) & 7)) & 1;

    float pd = 0.f, pa = 0.f, pm = -1e30f;
    float accd[Kk], acca[Kk], accm[Kk];
#pragma unroll
    for (int j = 0; j < Kk; ++j) { accd[j] = 0.f; acca[j] = 0.f; accm[j] = -1e30f; }

    for (int i = 0; i < 8; ++i) {
        int px = ch * 1024 + (i * 32 + l) * 4;
        float4 sc[Kk];
#pragma unroll
        for (int j = 0; j < Kk; ++j) {
            int plane = (g + j) & 7;
            sc[j] = ld4(shp + (size_t)(plane * Bb + b) * HW + px);
        }
        float4 sdg = ld4(sd + (size_t)(g * Bb + b) * HW + px);
        float4 P = ld4(Pbuf + bHW + px);           // fresh by barrier; L1-hot
        float4 sg = sc[0];                         // target plane == slot 0

#define SPEC_J(j) if (um[j]) { float u = 1.f - SCV * P_; float tt = m_ * u; \
        acca[j] += tt; accm[j] = fmaxf(accm[j], tt); accd[j] = fmaf(v_, u, accd[j]); }
#define DO_ELEM(e) { float P_ = P.e; float m_ = sg.e * P_; float v_ = sdg.e * P_; \
        pd += v_; pa += m_; pm = fmaxf(pm, m_); \
        { float SCV=sc[0].e; SPEC_J(0) } { float SCV=sc[1].e; SPEC_J(1) } \
        { float SCV=sc[2].e; SPEC_J(2) } { float SCV=sc[3].e; SPEC_J(3) } \
        { float SCV=sc[4].e; SPEC_J(4) } { float SCV=sc[5].e; SPEC_J(5) } \
        { float SCV=sc[6].e; SPEC_J(6) } { float SCV=sc[7].e; SPEC_J(7) } }
        DO_ELEM(x) DO_ELEM(y) DO_ELEM(z) DO_ELEM(w)
#undef DO_ELEM
#undef SPEC_J
    }

    __shared__ float ls[Kk][32][29];
    float* mine = ls[g][l];
#pragma unroll
    for (int j = 0; j < Kk; ++j) {
        mine[j * 3 + 0] = accd[j]; mine[j * 3 + 1] = acca[j]; mine[j * 3 + 2] = accm[j];
    }
    mine[24] = pd; mine[25] = pa; mine[26] = pm;
    __syncthreads();
    for (int st = 16; st > 0; st >>= 1) {
        if (l < st) {
            float* other = ls[g][l + st];
#pragma unroll
            for (int q = 0; q < QK; ++q)
                mine[q] = (q % 3 == 2) ? fmaxf(mine[q], other[q]) : (mine[q] + other[q]);
        }
        __syncthreads();
    }
    if (l == 0) {
#pragma unroll
        for (int j = 0; j < Kk; ++j) {
            int c = (g + j) & 7;
#pragma unroll
            for (int comp = 0; comp < 3; ++comp)
                pcur[(size_t)b * PARTN + (size_t)(g * QK + c * 3 + comp) * NCH + ch] = mine[j * 3 + comp];
        }
#pragma unroll
        for (int q = 24; q < QK; ++q)
            pcur[(size_t)b * PARTN + (size_t)(g * QK + q) * NCH + ch] = mine[q];
    }
}

// ---------------------------------------------------------------------------
// Kernel 3: gather (4 float4/thread). img0=192, grid 1728 in the ws path
// (only t=6,7 remain); img0=0, grid 6912 in the fallback path.
// ---------------------------------------------------------------------------
__global__ __launch_bounds__(256) void k_gather(
    const float* __restrict__ apc, const float* __restrict__ partials6,
    const float* __restrict__ zeta, float* idxf, float* __restrict__ out,
    int img0)
{
    int image = img0 + blockIdx.x / 27;    // 0..255 == t*32+b
    int chunk = blockIdx.x % 27;
    int t = image >> 5, b = image & 31;
    int tid = threadIdx.x;

    int s;
    if (t >= 6) {
        __shared__ float sv[24];
        __shared__ int s_ia, s_ib, s_mask;
        run_head(partials6, zeta, idxf, b, 8, (t == 6 && chunk == 0), tid,
                 sv, &s_ia, &s_ib, &s_mask);
        s = (t == 6) ? s_ia : s_ib;
    } else {
        s = clampK((int)idxf[t * Bb + b]);
    }

    const float4* src = reinterpret_cast<const float4*>(apc) + (size_t)(s * Bb + b) * CHW4;
    float4* dst = reinterpret_cast<float4*>(out) + (size_t)(image + Bb) * CHW4;
    int base = chunk * 1024 + tid;
    float4 r0 = src[base];
    float4 r1 = src[base + 256];
    float4 r2 = src[base + 512];
    float4 r3 = src[base + 768];
    dst[base]       = r0;
    dst[base + 256] = r1;
    dst[base + 512] = r2;
    dst[base + 768] = r3;
}

// ---------------------------------------------------------------------------
// Round 17: spec0 fused into pre as phase B (reads sd/shp L1-hot right after
// writing them; kills a 23.6us kernel for ~+12us pre growth). Plane-slot
// rotation in spec kernels (target = slot 0; drops the duplicate sg load;
// summation order per candidate identical to r12/r14). Race-free P phase
// retained from r16 (passed). 5 launches.
// ---------------------------------------------------------------------------
extern "C" void kernel_launch(void* const* d_in, const int* in_sizes, int n_in,
                              void* d_out, int out_size, void* d_ws, size_t ws_size,
                              hipStream_t stream)
{
    const float *images = nullptr, *apc = nullptr, *shp = nullptr;
    const float *zeta = nullptr, *back = nullptr;
    for (int i = 0; i < n_in; ++i) {
        int s = in_sizes[i];
        if (s == 28311552)      apc  = (const float*)d_in[i];
        else if (s == 9437184)  shp  = (const float*)d_in[i];
        else if (s == 256)      zeta = (const float*)d_in[i];
        else if (s == 3538944) {
            if (!images) images = (const float*)d_in[i];
            else         back   = (const float*)d_in[i];
        }
    }
    if (!images || !apc || !shp || !zeta || !back) {   // fallback: dict order
        images = (const float*)d_in[0]; apc = (const float*)d_in[1];
        shp = (const float*)d_in[2]; zeta = (const float*)d_in[3];
        back = (const float*)d_in[4];
    }
    float* out = (float*)d_out;
    float* idxf = out + OUTMAIN;                       // 256-element tail

    int has_ws = (d_ws != nullptr && ws_size >= (size_t)48 * 1024 * 1024);
    // Scratch: sd(9437184) + Pbuf(1179648) + pA(248832) + pB(248832) = 44.5MB
    float* sd = has_ws ? (float*)d_ws
                       : (out + BCHW);   // alias into out[1..8], dead before gather
    float* Pbuf = sd + 9437184;
    float* pA   = Pbuf + 1179648;
    float* pB   = pA + 248832;

    k_pre_spec0<<<1152, 256, 0, stream>>>(images, apc, shp, zeta, back, out, sd, pA);
    k_spec<<<1152, 256, 0, stream>>>(shp, sd, Pbuf, idxf, zeta, pA, pB, apc, out, 2, has_ws);
    k_spec<<<1152, 256, 0, stream>>>(shp, sd, Pbuf, idxf, zeta, pB, pA, apc, out, 4, has_ws);
    k_spec<<<1152, 256, 0, stream>>>(shp, sd, Pbuf, idxf, zeta, pA, pB, apc, out, 6, has_ws);
    if (has_ws) {
        k_gather<<<1728, 256, 0, stream>>>(apc, pB, zeta, idxf, out, 192);
    } else {
        k_gather<<<6912, 256, 0, stream>>>(apc, pB, zeta, idxf, out, 0);
    }
}

// Round 18
// 213.562 us; speedup vs baseline: 1.0598x; 1.0598x over previous
//
#include <hip/hip_runtime.h>
#include <math.h>

#define Kk 8
#define Bb 32
#define Cc 3
#define HW 36864          // 192*192
#define HW4 9216          // float4s per plane
#define CHW 110592        // 3*HW
#define CHW4 27648        // float4s per (k,b) image
#define BCHW 3538944      // B*C*HW
#define OUTMAIN 31850496  // 9*BCHW : index tail start in d_out (elements)
#define NCH 36            // chunks per batch (1024 px each)
#define QK 27             // per-k partial slots: spec[c][3] (24) + plain[3]
#define PARTN 7776        // 8*QK*NCH per batch
#define INVVAR 11.11111111111111f
#define EPSf 1e-5f

__device__ __forceinline__ int clampK(int v) { return v < 0 ? 0 : (v > Kk - 1 ? Kk - 1 : v); }
__device__ __forceinline__ float4 ld4(const float* p) { return *reinterpret_cast<const float4*>(p); }
__device__ __forceinline__ void st4(float* p, float4 v) { *reinterpret_cast<float4*>(p) = v; }

// ---------------------------------------------------------------------------
// Kernel 1: recon -> out[0] AND sd = shp*sum_c(apc-img)^2  (round-7 body).
// grid: 1152 x 256, 1 float4/thread.
// ---------------------------------------------------------------------------
__global__ __launch_bounds__(256) void k_pre_fused(
    const float* __restrict__ images, const float* __restrict__ apc,
    const float* __restrict__ shp, const float* __restrict__ zeta,
    const float* __restrict__ back, float* __restrict__ out,
    float* __restrict__ sd)
{
    int gid = blockIdx.x * 256 + threadIdx.x;
    int b = gid / HW4;
    int pix = (gid - b * HW4) * 4;

    float4 img[Cc], bk[Cc], rec[Cc];
#pragma unroll
    for (int c = 0; c < Cc; ++c) {
        img[c] = ld4(images + (size_t)(b * Cc + c) * HW + pix);
        bk[c]  = ld4(back   + (size_t)(b * Cc + c) * HW + pix);
        rec[c] = make_float4(0.f, 0.f, 0.f, 0.f);
    }
    float cum0 = 1.f, cum1 = 1.f, cum2 = 1.f, cum3 = 1.f;

#pragma unroll
    for (int k = 0; k < Kk; ++k) {
        float4 s = ld4(shp + (size_t)(k * Bb + b) * HW + pix);
        float z = zeta[k * Bb + b];
        float x0 = s.x * z, x1 = s.y * z, x2 = s.z * z, x3 = s.w * z;
        float g0 = x0 * cum0, g1 = x1 * cum1, g2 = x2 * cum2, g3 = x3 * cum3;
        float df0 = 0.f, df1 = 0.f, df2 = 0.f, df3 = 0.f;
#pragma unroll
        for (int c = 0; c < Cc; ++c) {
            float4 av = ld4(apc + ((size_t)(k * Bb + b) * Cc + c) * HW + pix);
            float d0 = av.x - img[c].x, d1 = av.y - img[c].y;
            float d2 = av.z - img[c].z, d3 = av.w - img[c].w;
            df0 += d0 * d0; df1 += d1 * d1; df2 += d2 * d2; df3 += d3 * d3;
            rec[c].x += g0 * av.x; rec[c].y += g1 * av.y;
            rec[c].z += g2 * av.z; rec[c].w += g3 * av.w;
        }
        st4(sd + (size_t)(k * Bb + b) * HW + pix,
            make_float4(s.x * df0, s.y * df1, s.z * df2, s.w * df3));
        cum0 *= (1.f - x0); cum1 *= (1.f - x1); cum2 *= (1.f - x2); cum3 *= (1.f - x3);
    }
#pragma unroll
    for (int c = 0; c < Cc; ++c) {
        st4(out + (size_t)(b * Cc + c) * HW + pix,
            make_float4(rec[c].x + cum0 * bk[c].x, rec[c].y + cum1 * bk[c].y,
                        rec[c].z + cum2 * bk[c].z, rec[c].w + cum3 * bk[c].w));
    }
}

// ---------------------------------------------------------------------------
// Head: resolve idx_{t-2} (plain) then idx_{t-1} (spec slice). Unchanged r12.
// ---------------------------------------------------------------------------
__device__ __forceinline__ void run_head(
    const float* __restrict__ pprev, const float* __restrict__ zeta,
    float* idxf, int b, int t, int write_idx, int tid,
    float* sv, int* s_ia, int* s_ib, int* s_mask)
{
    if (tid < 24) {
        int k = tid / 3, comp = tid - k * 3;
        float v = (comp == 2) ? -1e30f : 0.f;
        const float* src = pprev + (size_t)b * PARTN + (size_t)(k * QK + 24 + comp) * NCH;
        for (int j = 0; j < NCH; ++j) {
            float x = src[j];
            v = (comp == 2) ? fmaxf(v, x) : (v + x);
        }
        sv[tid] = v;
    }
    __syncthreads();
    if (tid == 0) {
        float best = -1e30f; int bi = 0;
        for (int k = 0; k < Kk; ++k) {
            float coef = 1.f;
            for (int j = 0; j < t - 2; ++j)
                if (clampK((int)idxf[j * Bb + b]) == k) coef = -1.f;
            float sc = coef * sv[3 * k + 2] * zeta[k * Bb + b] *
                       expf(-0.5f * INVVAR * sv[3 * k + 0] / (sv[3 * k + 1] + EPSf));
            if (sc > best) { best = sc; bi = k; }
        }
        *s_ia = bi;
    }
    __syncthreads();
    int ia = *s_ia;
    if (tid < 24) {
        int k = tid / 3, comp = tid - k * 3;
        float v = (comp == 2) ? -1e30f : 0.f;
        const float* src = pprev + (size_t)b * PARTN + (size_t)(k * QK + ia * 3 + comp) * NCH;
        for (int j = 0; j < NCH; ++j) {
            float x = src[j];
            v = (comp == 2) ? fmaxf(v, x) : (v + x);
        }
        sv[tid] = v;
    }
    __syncthreads();
    if (tid == 0) {
        float best = -1e30f; int bi = 0;
        for (int k = 0; k < Kk; ++k) {
            float coef = 1.f;
            for (int j = 0; j < t - 2; ++j)
                if (clampK((int)idxf[j * Bb + b]) == k) coef = -1.f;
            if (ia == k) coef = -1.f;
            float sc = coef * sv[3 * k + 2] * zeta[k * Bb + b] *
                       expf(-0.5f * INVVAR * sv[3 * k + 0] / (sv[3 * k + 1] + EPSf));
            if (sc > best) { best = sc; bi = k; }
        }
        *s_ib = bi;
        int mask = 0xFF;
        for (int j = 0; j < t - 2; ++j) mask &= ~(1 << clampK((int)idxf[j * Bb + b]));
        mask &= ~(1 << ia); mask &= ~(1 << bi);
        *s_mask = mask;
        if (write_idx) {
            idxf[(t - 2) * Bb + b] = (float)ia;
            idxf[(t - 1) * Bb + b] = (float)bi;
        }
    }
    __syncthreads();
}

// ---------------------------------------------------------------------------
// Kernel 2 (t=0,2,4,6): head -> fused copies -> race-free P phase ->
// accumulate (rotated windows). Exact round-16 body (213.3us, passed).
// grid: 1152 x 256. partials: [b][k*27 + (c*3+comp | 24..26 plain)][ch]
// ---------------------------------------------------------------------------
__global__ __launch_bounds__(256, 4) void k_spec(
    const float* __restrict__ shp, const float* __restrict__ sd,
    float* __restrict__ Pbuf, float* idxf, const float* __restrict__ zeta,
    const float* __restrict__ pprev, float* __restrict__ pcur,
    const float* __restrict__ apc, float* __restrict__ gout,
    int t, int do_copy)
{
    int b = blockIdx.x / NCH, ch = blockIdx.x % NCH;
    int tid = threadIdx.x;
    int g = tid >> 5, l = tid & 31;

    __shared__ float sv[24];
    __shared__ int s_ia, s_ib, s_mask;

    if (t == 0) {
        if (tid == 0) { s_ia = 0; s_ib = 0; s_mask = 0xFF; }
        __syncthreads();
    } else {
        run_head(pprev, zeta, idxf, b, t, (ch == 0), tid, sv, &s_ia, &s_ib, &s_mask);
    }
    int ia = s_ia, ib = s_ib, mask = s_mask;

    // ---- fused gather copy for steps t-2, t-1 (ws path only) ----
    if (do_copy && t > 0) {
        const float4* apc4 = reinterpret_cast<const float4*>(apc);
        float4* out4 = reinterpret_cast<float4*>(gout);
        const float4* src0 = apc4 + (size_t)(ia * Bb + b) * CHW4;
        const float4* src1 = apc4 + (size_t)(ib * Bb + b) * CHW4;
        float4* dst0 = out4 + (size_t)((t - 1) * Bb + b) * CHW4;   // out[1+(t-2)]
        float4* dst1 = out4 + (size_t)(t * Bb + b) * CHW4;         // out[1+(t-1)]
        int cb = ch * 768 + tid;
#pragma unroll
        for (int i = 0; i < 3; ++i) {
            dst0[cb + i * 256] = src0[cb + i * 256];
            dst1[cb + i * 256] = src1[cb + i * 256];
        }
    }

    const size_t bHW = (size_t)b * HW;

    // ---- P PHASE (t>0): thread tid owns float4 #tid of the chunk ----
    if (t > 0) {
        int px = ch * 1024 + tid * 4;
        float4 p0 = make_float4(1.f, 1.f, 1.f, 1.f);
        if (t > 2) p0 = ld4(Pbuf + bHW + px);
        float4 sa = ld4(shp + (size_t)(ia * Bb + b) * HW + px);
        float4 sb = ld4(shp + (size_t)(ib * Bb + b) * HW + px);
        float4 p1, P;
        p1.x = p0.x * (1.f - sa.x * p0.x); p1.y = p0.y * (1.f - sa.y * p0.y);
        p1.z = p0.z * (1.f - sa.z * p0.z); p1.w = p0.w * (1.f - sa.w * p0.w);
        P.x = p1.x * (1.f - sb.x * p1.x); P.y = p1.y * (1.f - sb.y * p1.y);
        P.z = p1.z * (1.f - sb.z * p1.z); P.w = p1.w * (1.f - sb.w * p1.w);
        st4(Pbuf + bHW + px, P);
        __syncthreads();
    }

    // ---- accumulate: group g targets k=g; rotated windows ----
    float pd = 0.f, pa = 0.f, pm = -1e30f;
    float accd[Kk], acca[Kk], accm[Kk];
#pragma unroll
    for (int c = 0; c < Kk; ++c) { accd[c] = 0.f; acca[c] = 0.f; accm[c] = -1e30f; }

    const int rot = g & 1;                    // odd groups lead by one window
    for (int i = 0; i < 8; ++i) {
        int win = (i + rot) & 7;
        int px = ch * 1024 + (win * 32 + l) * 4;
        float4 sc0 = ld4(shp + (size_t)(0 * Bb + b) * HW + px);
        float4 sc1 = ld4(shp + (size_t)(1 * Bb + b) * HW + px);
        float4 sc2 = ld4(shp + (size_t)(2 * Bb + b) * HW + px);
        float4 sc3 = ld4(shp + (size_t)(3 * Bb + b) * HW + px);
        float4 sc4 = ld4(shp + (size_t)(4 * Bb + b) * HW + px);
        float4 sc5 = ld4(shp + (size_t)(5 * Bb + b) * HW + px);
        float4 sc6 = ld4(shp + (size_t)(6 * Bb + b) * HW + px);
        float4 sc7 = ld4(shp + (size_t)(7 * Bb + b) * HW + px);
        float4 sdg = ld4(sd  + (size_t)(g * Bb + b) * HW + px);
        float4 sg  = ld4(shp + (size_t)(g * Bb + b) * HW + px);   // L1 hit

        float4 P = make_float4(1.f, 1.f, 1.f, 1.f);
        if (t > 0) P = ld4(Pbuf + bHW + px);    // fresh by the barrier; L1-hot

#define SPEC_C(c, scv) if (mask & (1 << c)) { \
        float u = 1.f - scv * P_; float tt = m_ * u; \
        acca[c] += tt; accm[c] = fmaxf(accm[c], tt); accd[c] = fmaf(v_, u, accd[c]); }
#define DO_ELEM(e) { float P_ = P.e; float m_ = sg.e * P_; float v_ = sdg.e * P_; \
        pd += v_; pa += m_; pm = fmaxf(pm, m_); \
        SPEC_C(0, sc0.e) SPEC_C(1, sc1.e) SPEC_C(2, sc2.e) SPEC_C(3, sc3.e) \
        SPEC_C(4, sc4.e) SPEC_C(5, sc5.e) SPEC_C(6, sc6.e) SPEC_C(7, sc7.e) }
        DO_ELEM(x) DO_ELEM(y) DO_ELEM(z) DO_ELEM(w)
#undef DO_ELEM
#undef SPEC_C
    }

    // LDS reduce: per k-group (32 lanes), 27 values. stride 29 (coprime 32).
    __shared__ float ls[8][32][29];
    float* mine = ls[g][l];
#pragma unroll
    for (int c = 0; c < Kk; ++c) {
        mine[c * 3 + 0] = accd[c]; mine[c * 3 + 1] = acca[c]; mine[c * 3 + 2] = accm[c];
    }
    mine[24] = pd; mine[25] = pa; mine[26] = pm;
    __syncthreads();
    for (int st = 16; st > 0; st >>= 1) {
        if (l < st) {
            float* other = ls[g][l + st];
#pragma unroll
            for (int q = 0; q < QK; ++q)
                mine[q] = (q % 3 == 2) ? fmaxf(mine[q], other[q]) : (mine[q] + other[q]);
        }
        __syncthreads();
    }
    if (l == 0) {
#pragma unroll
        for (int q = 0; q < QK; ++q)
            pcur[(size_t)b * PARTN + (size_t)(g * QK + q) * NCH + ch] = mine[q];
    }
}

// ---------------------------------------------------------------------------
// Kernel 3: gather (4 float4/thread). img0=192, grid 1728 in the ws path
// (only t=6,7 remain); img0=0, grid 6912 in the fallback path.
// ---------------------------------------------------------------------------
__global__ __launch_bounds__(256) void k_gather(
    const float* __restrict__ apc, const float* __restrict__ partials6,
    const float* __restrict__ zeta, float* idxf, float* __restrict__ out,
    int img0)
{
    int image = img0 + blockIdx.x / 27;    // 0..255 == t*32+b
    int chunk = blockIdx.x % 27;
    int t = image >> 5, b = image & 31;
    int tid = threadIdx.x;

    int s;
    if (t >= 6) {
        __shared__ float sv[24];
        __shared__ int s_ia, s_ib, s_mask;
        run_head(partials6, zeta, idxf, b, 8, (t == 6 && chunk == 0), tid,
                 sv, &s_ia, &s_ib, &s_mask);
        s = (t == 6) ? s_ia : s_ib;
    } else {
        s = clampK((int)idxf[t * Bb + b]);
    }

    const float4* src = reinterpret_cast<const float4*>(apc) + (size_t)(s * Bb + b) * CHW4;
    float4* dst = reinterpret_cast<float4*>(out) + (size_t)(image + Bb) * CHW4;
    int base = chunk * 1024 + tid;
    float4 r0 = src[base];
    float4 r1 = src[base + 256];
    float4 r2 = src[base + 512];
    float4 r3 = src[base + 768];
    dst[base]       = r0;
    dst[base + 256] = r1;
    dst[base + 512] = r2;
    dst[base + 768] = r3;
}

// ---------------------------------------------------------------------------
// Round 18: exact revert to round 16 (213.3us, passed) — the session optimum.
// r17's pre+spec0 fusion regressed (+13us; FETCH +35MB: phase B's "L1-hot"
// re-reads actually missed L2 under chip-wide store traffic). Structural
// consolidations beyond this point (r10, r17) are consistently net-negative;
// pre's ~2x path-efficiency cap survived 3 falsified theories (width,
// occupancy/MLP, asm batching) and spec's L1 thrash survived 2 (LDS staging,
// rotation). Locking in the best measured configuration.
// ---------------------------------------------------------------------------
extern "C" void kernel_launch(void* const* d_in, const int* in_sizes, int n_in,
                              void* d_out, int out_size, void* d_ws, size_t ws_size,
                              hipStream_t stream)
{
    const float *images = nullptr, *apc = nullptr, *shp = nullptr;
    const float *zeta = nullptr, *back = nullptr;
    for (int i = 0; i < n_in; ++i) {
        int s = in_sizes[i];
        if (s == 28311552)      apc  = (const float*)d_in[i];
        else if (s == 9437184)  shp  = (const float*)d_in[i];
        else if (s == 256)      zeta = (const float*)d_in[i];
        else if (s == 3538944) {
            if (!images) images = (const float*)d_in[i];
            else         back   = (const float*)d_in[i];
        }
    }
    if (!images || !apc || !shp || !zeta || !back) {   // fallback: dict order
        images = (const float*)d_in[0]; apc = (const float*)d_in[1];
        shp = (const float*)d_in[2]; zeta = (const float*)d_in[3];
        back = (const float*)d_in[4];
    }
    float* out = (float*)d_out;
    float* idxf = out + OUTMAIN;                       // 256-element tail

    int has_ws = (d_ws != nullptr && ws_size >= (size_t)48 * 1024 * 1024);
    // Scratch: sd(9437184) + Pbuf(1179648) + pA(248832) + pB(248832) = 44.5MB
    float* sd = has_ws ? (float*)d_ws
                       : (out + BCHW);   // alias into out[1..8], dead before gather
    float* Pbuf = sd + 9437184;
    float* pA   = Pbuf + 1179648;
    float* pB   = pA + 248832;

    k_pre_fused<<<1152, 256, 0, stream>>>(images, apc, shp, zeta, back, out, sd);
    k_spec<<<1152, 256, 0, stream>>>(shp, sd, Pbuf, idxf, zeta, pB, pA, apc, out, 0, has_ws);
    k_spec<<<1152, 256, 0, stream>>>(shp, sd, Pbuf, idxf, zeta, pA, pB, apc, out, 2, has_ws);
    k_spec<<<1152, 256, 0, stream>>>(shp, sd, Pbuf, idxf, zeta, pB, pA, apc, out, 4, has_ws);
    k_spec<<<1152, 256, 0, stream>>>(shp, sd, Pbuf, idxf, zeta, pA, pB, apc, out, 6, has_ws);
    if (has_ws) {
        k_gather<<<1728, 256, 0, stream>>>(apc, pB, zeta, idxf, out, 192);
    } else {
        k_gather<<<6912, 256, 0, stream>>>(apc, pB, zeta, idxf, out, 0);
    }
}